// Round 13
// baseline (343.766 us; speedup 1.0000x reference)
//
#include <hip/hip_runtime.h>

#define NL 16384          // row length
#define NB 64             // rows = blocks
#define NDT 512           // data threads (8 waves)
#define NT  576           // +1 dedicated barrier wave
#define NC (NL / NDT)     // 32 elements per thread == bits in the peak mask
#define NW (NDT / 64)     // 8 data waves
#define N_ITER 12
#define N_IMFS 6

#pragma clang fp contract(off)   // everything unfused EXCEPT the explicit fmaf

#define HSZ (NL + (NL >> 5))   // +1 float per 32: 2-way-max banking (free)
__device__ __forceinline__ int physi(int i) { return i + (i >> 5); }

#define FMAXV 3.402823466e38f

// Frozen bit-exact semantics (certified R9/R12, absmax 0.0). Structure: 1-deep
// speculative sifting — subtract h-=mean BEFORE the grid decision resolves,
// backing up pre-subtract h bits into meanb; wave 8 (t>=NDT) resolves the
// grid barrier + sd decision concurrently with the data waves' next pass A.
// On the rare freeze, restore h from backup (bitwise) — matches the JAX
// done-latch (h kept unsubtracted on the converging iteration) exactly.
__global__ __launch_bounds__(NT, 1) void emd_main(
    const float* __restrict__ x, float* __restrict__ out,
    unsigned* cnt, double* sdsl, double* flsl) {
  __shared__ float h[HSZ];        // 67584 B
  __shared__ float meanb[HSZ];    // 67584 B: mean, then pre-subtract h backup
  __shared__ int wLU[NW], wLL[NW], wNU[NW], wNL[NW];
  __shared__ float wMx[NW], wMn[NW];
  __shared__ unsigned wCT[NW];
  __shared__ int eLU[NW], eLL[NW], eNU[NW], eNL[NW];
  __shared__ float eMx[NW], eMn[NW];
  __shared__ unsigned sTot;
  __shared__ double tA[NW], tB[NW], tC[NW], tD[NW];
  __shared__ int sFlag;

  const int t = threadIdx.x;
  const int lane = t & 63;
  const int wv = t >> 6;
  const bool dataT = (t < NDT);
  const int row = blockIdx.x;
  const int base = t * NC;
  const float* xr = x + (size_t)row * NL;
  float* res = out + (size_t)N_IMFS * NB * NL + (size_t)row * NL;

  if (dataT) {
    for (int m = 0; m < NC; m++) {
      int i = m * NDT + t;
      float v = xr[i];
      h[physi(i)] = v;
      res[i] = v;
    }
  }
  __syncthreads();

  unsigned ep = 0;
  bool done = false;

  for (int k = 0; k < N_IMFS; k++) {
    float* outk = out + (size_t)k * NB * NL + (size_t)row * NL;
    if (done) {  // globally-uniform skip (no barriers)
      if (dataT) for (int m = 0; m < NC; m++) outk[m * NDT + t] = 0.0f;
      continue;
    }

    // S-state registers (persist across the pipelined loop)
    unsigned mU = 0, mL = 0;
    int iLU = -1, iLL = -1, iNU = NL, iNL = NL;
    float iMx = -FMAXV, iMn = FMAXV;

    // -------- pipelined sifting: S(it) at top; flag(it-1) resolved by wave8 --------
    for (int it = 0; it <= N_ITER; it++) {
      // ---- stage S: pass A + wave scans on current h (dataT) ----
      // ---- wave8: concurrently resolve grid barrier + decision for it-1 ----
      if (dataT) {
        mU = 0; mL = 0;
        int lmU = -1, lmL = -1, cU = 0, cL = 0;
        float rmx = -FMAXV, rmn = FMAXV;
        float hm = (base > 0) ? h[physi(base - 1)] : 0.0f;
        float hc = h[physi(base)];
        #pragma unroll
        for (int j = 0; j < NC; j++) {
          int i = base + j;
          float hp = (i + 1 < NL) ? h[physi(i + 1)] : 0.0f;
          bool in = (i > 0) && (i + 1 < NL);
          if (in && hm < hc && hc > hp) { mU |= (1u << j); lmU = i; cU++; }
          if (in && hm > hc && hc < hp) { mL |= (1u << j); lmL = i; cL++; }
          rmx = fmaxf(rmx, hc);
          rmn = fminf(rmn, hc);
          hm = hc; hc = hp;
        }
        iLU = lmU; iLL = lmL; iMx = rmx; iMn = rmn;
        iNU = mU ? (base + __ffs(mU) - 1) : NL;
        iNL = mL ? (base + __ffs(mL) - 1) : NL;
        unsigned ict = ((unsigned)cU << 16) | (unsigned)cL;
        #pragma unroll
        for (int o = 1; o < 64; o <<= 1) {
          int a = __shfl_up(iLU, o, 64);
          int b = __shfl_up(iLL, o, 64);
          float fa = __shfl_up(iMx, o, 64);
          float fb = __shfl_up(iMn, o, 64);
          int c = __shfl_down(iNU, o, 64);
          int d = __shfl_down(iNL, o, 64);
          unsigned cc = __shfl_down(ict, o, 64);
          if (lane >= o) { iLU = max(iLU, a); iLL = max(iLL, b);
                           iMx = fmaxf(iMx, fa); iMn = fminf(iMn, fb); }
          if (lane + o < 64) { iNU = min(iNU, c); iNL = min(iNL, d); ict += cc; }
        }
        if (lane == 63) { wLU[wv] = iLU; wLL[wv] = iLL; wMx[wv] = iMx; wMn[wv] = iMn; }
        if (lane == 0)  { wNU[wv] = iNU; wNL[wv] = iNL; wCT[wv] = ict; }
      } else if (t == NDT && it > 0) {
        // spin for iteration it-1 (all blocks inc'd one sync ago) + decision
        unsigned tgt = ep * gridDim.x;
        while (__hip_atomic_load(cnt, __ATOMIC_ACQUIRE, __HIP_MEMORY_SCOPE_AGENT) < tgt)
          __builtin_amdgcn_s_sleep(1);
        int slot = k * N_ITER + (it - 1);
        double m2 = __hip_atomic_load(&sdsl[slot * 2 + 0],
                                      __ATOMIC_RELAXED, __HIP_MEMORY_SCOPE_AGENT);
        double h2 = __hip_atomic_load(&sdsl[slot * 2 + 1],
                                      __ATOMIC_RELAXED, __HIP_MEMORY_SCOPE_AGENT);
        sFlag = (m2 / (h2 + 1e-8) < 0.05) ? 1 : 0;
      }
      __syncthreads();   // (C)
      if (t == 0) {  // 8-entry serial combine -> exclusive wave carries
        int aLU = -1, aLL = -1; float aMx = -FMAXV, aMn = FMAXV; unsigned tot = 0;
        for (int w = 0; w < NW; w++) {
          eLU[w] = aLU; aLU = max(aLU, wLU[w]);
          eLL[w] = aLL; aLL = max(aLL, wLL[w]);
          eMx[w] = aMx; aMx = fmaxf(aMx, wMx[w]);
          eMn[w] = aMn; aMn = fminf(aMn, wMn[w]);
          tot += wCT[w];
        }
        int aNU = NL, aNL = NL;
        for (int w = NW - 1; w >= 0; w--) {
          eNU[w] = aNU; aNU = min(aNU, wNU[w]);
          eNL[w] = aNL; aNL = min(aNL, wNL[w]);
        }
        sTot = tot;
      }
      __syncthreads();   // (D)

      // resolve previous iteration's decision (uniform across blocks)
      if (it > 0 && sFlag) {
        // frozen: restore pre-subtract h bits from backup; stop sifting
        if (dataT) {
          #pragma unroll
          for (int q = 0; q < NC / 4; q++) {
            int p0 = physi(base + q * 4);
            *(float4*)&h[p0] = *(const float4*)&meanb[p0];
          }
        }
        __syncthreads();
        break;
      }
      if (it == N_ITER) break;   // exhausted (S of this round discarded)

      // final carries for this S
      int clU = 0, clL = 0, cnU = 0, cnL = 0, totU = 0, totL = 0;
      float crx = 0.0f, crn = 0.0f;
      if (dataT) {
        unsigned tot = sTot;
        totU = (int)(tot >> 16); totL = (int)(tot & 0xffffu);
        int pLU = __shfl_up(iLU, 1, 64); if (lane == 0) pLU = -1;
        int pLL = __shfl_up(iLL, 1, 64); if (lane == 0) pLL = -1;
        float pMx = __shfl_up(iMx, 1, 64); if (lane == 0) pMx = -FMAXV;
        float pMn = __shfl_up(iMn, 1, 64); if (lane == 0) pMn = FMAXV;
        int sNUl = __shfl_down(iNU, 1, 64); if (lane == 63) sNUl = NL;
        int sNLl = __shfl_down(iNL, 1, 64); if (lane == 63) sNLl = NL;
        clU = max(eLU[wv], pLU); clL = max(eLL[wv], pLL);
        crx = fmaxf(eMx[wv], pMx); crn = fminf(eMn[wv], pMn);
        cnU = min(eNU[wv], sNUl); cnL = min(eNL[wv], sNLl);
      }

      // ---- pass C: envelopes + mean (frozen f32 ladder) -> meanb; f64 sums ----
      double pm2 = 0.0, ph2 = 0.0;
      if (dataT) {
        float rx = crx, rn = crn;
        int gA = -0x7fffffff, gB = -0x7fffffff, gC = -0x7fffffff, gD = -0x7fffffff;
        float vl = 0.0f, vr = 0.0f, wl = 0.0f, wr = 0.0f;
        #pragma unroll
        for (int j = 0; j < NC; j++) {
          int i = base + j;
          float hc = h[physi(i)];
          rx = fmaxf(rx, hc);
          rn = fminf(rn, hc);
          unsigned lowm = 0xFFFFFFFFu >> (31 - j);   // bits <= j
          unsigned highm = 0xFFFFFFFFu << j;         // bits >= j
          unsigned a;
          a = mU & lowm;  int lU  = a ? (base + 31 - __clz(a)) : clU;
          a = mL & lowm;  int lL  = a ? (base + 31 - __clz(a)) : clL;
          a = mU & highm; int nUv = a ? (base + __ffs(a) - 1) : cnU;
          a = mL & highm; int nLv = a ? (base + __ffs(a) - 1) : cnL;
          if (lU != gA)  { gA = lU;  vl = h[physi(lU < 0 ? 0 : lU)]; }
          if (nUv != gB) { gB = nUv; vr = h[physi(nUv >= NL ? NL - 1 : nUv)]; }
          if (lL != gC)  { gC = lL;  wl = h[physi(lL < 0 ? 0 : lL)]; }
          if (nLv != gD) { gD = nLv; wr = h[physi(nLv >= NL ? NL - 1 : nLv)]; }
          int den = nUv - lU;
          float fracU = (float)(i - lU) / (float)(den > 0 ? den : 1);
          float envU = (den > 0) ? __builtin_fmaf(fracU, vr - vl, vl) : vl;
          if (lU < 0) envU = vr;
          if (nUv >= NL) envU = vl;
          if (totU < 2) envU = rx;
          int den2 = nLv - lL;
          float fracL = (float)(i - lL) / (float)(den2 > 0 ? den2 : 1);
          float envL = (den2 > 0) ? __builtin_fmaf(fracL, wr - wl, wl) : wl;
          if (lL < 0) envL = wr;
          if (nLv >= NL) envL = wl;
          if (totL < 2) envL = rn;
          float mn = 0.5f * (envU + envL);
          meanb[physi(i)] = mn;
          pm2 += (double)mn * (double)mn;
          ph2 += (double)hc * (double)hc;
        }
        // wave reduction + publish
        #pragma unroll
        for (int o = 1; o < 64; o <<= 1) {
          double a2 = __shfl_down(pm2, o, 64);
          double b2 = __shfl_down(ph2, o, 64);
          if (lane + o < 64) { pm2 += a2; ph2 += b2; }
        }
        if (lane == 0) { tA[wv] = pm2; tB[wv] = ph2; }
      }
      ep++;
      __syncthreads();   // (A): pass C h-reads done; tA/tB + meanb published
      // speculative subtract + backup (dataT); wave8: sums -> global, inc
      if (dataT) {
        #pragma unroll
        for (int q = 0; q < NC / 4; q++) {
          int p0 = physi(base + q * 4);
          float4 hv = *(const float4*)&h[p0];
          float4 mv = *(const float4*)&meanb[p0];
          float4 nh = make_float4(hv.x - mv.x, hv.y - mv.y, hv.z - mv.z, hv.w - mv.w);
          *(float4*)&h[p0] = nh;        // h -= mean (speculative)
          *(float4*)&meanb[p0] = hv;    // backup pre-subtract bits
        }
      } else if (t == NDT) {
        double sA = 0.0, sB = 0.0;
        for (int w = 0; w < NW; w++) { sA += tA[w]; sB += tB[w]; }
        int slot = k * N_ITER + it;
        atomicAdd(&sdsl[slot * 2 + 0], sA);
        atomicAdd(&sdsl[slot * 2 + 1], sB);
        __hip_atomic_fetch_add(cnt, 1u, __ATOMIC_ACQ_REL, __HIP_MEMORY_SCOPE_AGENT);
      }
      __syncthreads();   // (B): h updated; this block's sums committed + inc'd
    }

    // ------------- flatness test + outputs (f32 values, f64 sums) -------------
    double s1 = 0.0, s2 = 0.0, s3 = 0.0, s4 = 0.0;
    if (dataT) {
      float rc = res[base] - h[physi(base)];
      #pragma unroll
      for (int j = 0; j < NC; j++) {
        int i = base + j;
        s1 += (double)rc;
        s2 += (double)rc * (double)rc;
        if (i + 1 < NL) {
          float rnx = res[i + 1] - h[physi(i + 1)];
          float d = rnx - rc;
          s3 += (double)d;
          s4 += (double)d * (double)d;
          rc = rnx;
        }
      }
      #pragma unroll
      for (int o = 1; o < 64; o <<= 1) {
        double a = __shfl_down(s1, o, 64);
        double b = __shfl_down(s2, o, 64);
        double c = __shfl_down(s3, o, 64);
        double d = __shfl_down(s4, o, 64);
        if (lane + o < 64) { s1 += a; s2 += b; s3 += c; s4 += d; }
      }
      if (lane == 0) { tA[wv] = s1; tB[wv] = s2; tC[wv] = s3; tD[wv] = s4; }
    }
    __syncthreads();   // orders publishes AND all cross-thread h/res reads above
    if (t == 0) {
      double S1 = 0.0, S2 = 0.0, S3 = 0.0, S4 = 0.0;
      for (int w = 0; w < NW; w++) { S1 += tA[w]; S2 += tB[w]; S3 += tC[w]; S4 += tD[w]; }
      atomicAdd(&flsl[k * 4 + 0], S1);
      atomicAdd(&flsl[k * 4 + 1], S2);
      atomicAdd(&flsl[k * 4 + 2], S3);
      atomicAdd(&flsl[k * 4 + 3], S4);
    }
    // outputs: IMF k = h; res -= h; h <- new res
    if (dataT) {
      #pragma unroll
      for (int q = 0; q < NC / 4; q++) {
        int i0 = base + q * 4;
        int p0 = physi(i0);
        float4 rv = *(const float4*)&res[i0];
        float4 hv = *(const float4*)&h[p0];
        float4 rq = make_float4(rv.x - hv.x, rv.y - hv.y, rv.z - hv.z, rv.w - hv.w);
        *(float4*)&outk[i0] = hv;
        *(float4*)&res[i0] = rq;
        *(float4*)&h[p0] = rq;
      }
    }
    // ---- grid barrier + flatness decision ----
    ep++;
    __syncthreads();
    if (t == 0) {
      __hip_atomic_fetch_add(cnt, 1u, __ATOMIC_ACQ_REL, __HIP_MEMORY_SCOPE_AGENT);
      unsigned tgt = ep * gridDim.x;
      while (__hip_atomic_load(cnt, __ATOMIC_ACQUIRE, __HIP_MEMORY_SCOPE_AGENT) < tgt)
        __builtin_amdgcn_s_sleep(1);
      double S1 = __hip_atomic_load(&flsl[k * 4 + 0], __ATOMIC_RELAXED, __HIP_MEMORY_SCOPE_AGENT);
      double S2 = __hip_atomic_load(&flsl[k * 4 + 1], __ATOMIC_RELAXED, __HIP_MEMORY_SCOPE_AGENT);
      double S3 = __hip_atomic_load(&flsl[k * 4 + 2], __ATOMIC_RELAXED, __HIP_MEMORY_SCOPE_AGENT);
      double S4 = __hip_atomic_load(&flsl[k * 4 + 3], __ATOMIC_RELAXED, __HIP_MEMORY_SCOPE_AGENT);
      double nr = (double)NB * (double)NL;
      double nd = (double)NB * (double)(NL - 1);
      double varr = (S2 - S1 * S1 / nr) / (nr - 1.0);
      double vard = (S4 - S3 * S3 / nd) / (nd - 1.0);
      sFlag = (vard < 0.05 * varr) ? 1 : 0;
    }
    __syncthreads();
    done = done || (sFlag != 0);
  }
}

extern "C" void kernel_launch(void* const* d_in, const int* in_sizes, int n_in,
                              void* d_out, int out_size, void* d_ws, size_t ws_size,
                              hipStream_t stream) {
  const float* x = (const float*)d_in[0];
  float* out = (float*)d_out;
  // ws layout: [0] barrier counter; [256] sd slots (6*12*2 dbl); [1408] flat slots (6*4 dbl)
  size_t zb = ws_size < 4096 ? ws_size : 4096;
  hipMemsetAsync(d_ws, 0, zb, stream);
  unsigned* cnt = (unsigned*)d_ws;
  double* sdsl = (double*)((char*)d_ws + 256);
  double* flsl = (double*)((char*)d_ws + 256 + (size_t)N_IMFS * N_ITER * 2 * 8);
  hipLaunchKernelGGL(emd_main, dim3(NB), dim3(NT), 0, stream, x, out, cnt, sdsl, flsl);
}